// Round 1
// baseline (426.230 us; speedup 1.0000x reference)
//
#include <hip/hip_runtime.h>
#include <math.h>

#define B_ 4096
#define F_ 64
#define A_ 8
#define U_ 32
#define BT 64   // batch rows per block

// Per block (a, b-tile of 64 rows):
//   load X^T tile to LDS once; loop over j=0..63:
//     stage K[j,a] (f-major) and W^T = exp(2K) (u-major) in LDS
//     Z = X @ K  minus rank-1 mask correction x[:,j] * K[j,:]
//     row softmax over U (shfl over 16-lane groups)
//     S += P @ W^T  (P via LDS transpose)
//   S /= 64; row softmax over F; coalesced float4 store.
__global__ __launch_bounds__(256, 2)
void ife_kernel(const float* __restrict__ x,     // [B, F]
                const float* __restrict__ kern,  // [j=F, A, F, U]
                float* __restrict__ out)         // [A, B, F]
{
    const int a  = blockIdx.y;
    const int bt = blockIdx.x;
    const int t  = threadIdx.x;
    const int tr = t >> 4;   // 0..15 -> rows tr*4..tr*4+3
    const int tc = t & 15;   // 0..15

    __shared__ float Xt[F_][BT];   // [f][r]
    __shared__ float Kj[F_][U_];   // [f][u]
    __shared__ float Wt[U_][F_];   // [u][f] = exp(2*K[j,a,f,u])
    __shared__ float Pt[U_][BT];   // [u][r]

    // ---- load X tile (transposed into LDS) ----
    {
        const int r0 = t >> 4;          // 0..15
        const int f4 = (t & 15) * 4;    // 0..60
        #pragma unroll
        for (int i = 0; i < 4; ++i) {
            const int r = r0 + 16 * i;
            const float4 v = *(const float4*)&x[(size_t)(bt * BT + r) * F_ + f4];
            Xt[f4 + 0][r] = v.x;
            Xt[f4 + 1][r] = v.y;
            Xt[f4 + 2][r] = v.z;
            Xt[f4 + 3][r] = v.w;
        }
    }

    float S[4][4];
    #pragma unroll
    for (int i = 0; i < 4; ++i)
        #pragma unroll
        for (int k = 0; k < 4; ++k) S[i][k] = 0.f;

    for (int j = 0; j < F_; ++j) {
        __syncthreads();  // prev iter done reading Kj/Wt/Pt (also covers Xt store on j==0)

        // ---- stage K[j,a] and W^T = exp(2K) ----
        {
            const float* kbase = kern + ((size_t)j * A_ + a) * (F_ * U_);
            #pragma unroll
            for (int i = 0; i < 2; ++i) {
                const int idx = t + 256 * i;       // 0..511 (float4 id)
                const int f   = idx >> 3;
                const int u4  = (idx & 7) * 4;
                const float4 v = *(const float4*)&kbase[f * U_ + u4];
                *(float4*)&Kj[f][u4] = v;
                Wt[u4 + 0][f] = __expf(2.f * v.x);
                Wt[u4 + 1][f] = __expf(2.f * v.y);
                Wt[u4 + 2][f] = __expf(2.f * v.z);
                Wt[u4 + 3][f] = __expf(2.f * v.w);
            }
        }
        __syncthreads();

        // ---- Z = X @ K  (4 rows x 2 u-cols per thread) ----
        float z00 = 0.f, z01 = 0.f, z10 = 0.f, z11 = 0.f;
        float z20 = 0.f, z21 = 0.f, z30 = 0.f, z31 = 0.f;
        #pragma unroll
        for (int f = 0; f < F_; ++f) {
            const float4 xv = *(const float4*)&Xt[f][tr * 4];
            const float2 kv = *(const float2*)&Kj[f][tc * 2];
            z00 += xv.x * kv.x; z01 += xv.x * kv.y;
            z10 += xv.y * kv.x; z11 += xv.y * kv.y;
            z20 += xv.z * kv.x; z21 += xv.z * kv.y;
            z30 += xv.w * kv.x; z31 += xv.w * kv.y;
        }
        // rank-1 mask correction: remove feature j's contribution
        {
            const float4 xj = *(const float4*)&Xt[j][tr * 4];
            const float2 kj = *(const float2*)&Kj[j][tc * 2];
            z00 -= xj.x * kj.x; z01 -= xj.x * kj.y;
            z10 -= xj.y * kj.x; z11 -= xj.y * kj.y;
            z20 -= xj.z * kj.x; z21 -= xj.z * kj.y;
            z30 -= xj.w * kj.x; z31 -= xj.w * kj.y;
        }

        // ---- softmax over U (32 vals = 16 lanes x 2) ----
        {
            float za[4][2] = {{z00, z01}, {z10, z11}, {z20, z21}, {z30, z31}};
            #pragma unroll
            for (int ri = 0; ri < 4; ++ri) {
                float m = fmaxf(za[ri][0], za[ri][1]);
                m = fmaxf(m, __shfl_xor(m, 1));
                m = fmaxf(m, __shfl_xor(m, 2));
                m = fmaxf(m, __shfl_xor(m, 4));
                m = fmaxf(m, __shfl_xor(m, 8));
                const float e0 = __expf(za[ri][0] - m);
                const float e1 = __expf(za[ri][1] - m);
                float s = e0 + e1;
                s += __shfl_xor(s, 1);
                s += __shfl_xor(s, 2);
                s += __shfl_xor(s, 4);
                s += __shfl_xor(s, 8);
                const float inv = 1.f / s;
                Pt[tc * 2 + 0][tr * 4 + ri] = e0 * inv;
                Pt[tc * 2 + 1][tr * 4 + ri] = e1 * inv;
            }
        }
        __syncthreads();

        // ---- S += P @ W^T  (4 rows x 4 f-cols per thread) ----
        #pragma unroll
        for (int u = 0; u < U_; ++u) {
            const float4 pv = *(const float4*)&Pt[u][tr * 4];
            const float4 wv = *(const float4*)&Wt[u][tc * 4];
            S[0][0] += pv.x * wv.x; S[0][1] += pv.x * wv.y; S[0][2] += pv.x * wv.z; S[0][3] += pv.x * wv.w;
            S[1][0] += pv.y * wv.x; S[1][1] += pv.y * wv.y; S[1][2] += pv.y * wv.z; S[1][3] += pv.y * wv.w;
            S[2][0] += pv.z * wv.x; S[2][1] += pv.z * wv.y; S[2][2] += pv.z * wv.z; S[2][3] += pv.z * wv.w;
            S[3][0] += pv.w * wv.x; S[3][1] += pv.w * wv.y; S[3][2] += pv.w * wv.z; S[3][3] += pv.w * wv.w;
        }
    }

    // ---- mean over j, softmax over F, store ----
    const float inv64 = 1.f / 64.f;
    #pragma unroll
    for (int ri = 0; ri < 4; ++ri) {
        #pragma unroll
        for (int fi = 0; fi < 4; ++fi) S[ri][fi] *= inv64;

        float m = fmaxf(fmaxf(S[ri][0], S[ri][1]), fmaxf(S[ri][2], S[ri][3]));
        m = fmaxf(m, __shfl_xor(m, 1));
        m = fmaxf(m, __shfl_xor(m, 2));
        m = fmaxf(m, __shfl_xor(m, 4));
        m = fmaxf(m, __shfl_xor(m, 8));
        const float e0 = __expf(S[ri][0] - m);
        const float e1 = __expf(S[ri][1] - m);
        const float e2 = __expf(S[ri][2] - m);
        const float e3 = __expf(S[ri][3] - m);
        float s = e0 + e1 + e2 + e3;
        s += __shfl_xor(s, 1);
        s += __shfl_xor(s, 2);
        s += __shfl_xor(s, 4);
        s += __shfl_xor(s, 8);
        const float inv = 1.f / s;

        const int b = bt * BT + tr * 4 + ri;
        float4 o;
        o.x = e0 * inv; o.y = e1 * inv; o.z = e2 * inv; o.w = e3 * inv;
        *(float4*)&out[((size_t)a * B_ + b) * F_ + tc * 4] = o;
    }
}

extern "C" void kernel_launch(void* const* d_in, const int* in_sizes, int n_in,
                              void* d_out, int out_size, void* d_ws, size_t ws_size,
                              hipStream_t stream) {
    (void)in_sizes; (void)n_in; (void)d_ws; (void)ws_size; (void)out_size;
    const float* x    = (const float*)d_in[0];   // [B, F]
    const float* kern = (const float*)d_in[1];   // [F, A, F, U]
    float* out        = (float*)d_out;           // [A, B, F]

    dim3 grid(B_ / BT, A_);
    dim3 block(256);
    hipLaunchKernelGGL(ife_kernel, grid, block, 0, stream, x, kern, out);
}

// Round 2
// 185.183 us; speedup vs baseline: 2.3017x; 2.3017x over previous
//
#include <hip/hip_runtime.h>
#include <math.h>

#define B_ 4096
#define F_ 64
#define A_ 8
#define U_ 32

typedef float f32x4 __attribute__((ext_vector_type(4)));
typedef short bf16x8 __attribute__((ext_vector_type(8)));

// d_ws layout (8 MB + 64 KB needed):
//   [KH 2MB][KL 2MB][WH 2MB][WL 2MB][KDIAG 64KB]
// KH/KL: Z-GEMM B-frags, frag-linear: per (j,a): 4 frags (kc*2+utile) x 64 lanes x 16B
//   element: B[k=f=kc*32+q*8+jj][n=u=utile*16+c]  (hi / lo bf16 split of K)
// WH/WL: S-GEMM B-frags: per (j,a): 4 frags (ftile) x 64 lanes x 16B
//   element: B[k=u=q*8+jj][n=f=ftile*16+c] = exp(2*K[j,a][f][u]) split hi/lo
// KDIAG: fp32 K[j,a][j][u] for the rank-1 mask correction
#define KH_OFF 0ull
#define KL_OFF 2097152ull
#define WH_OFF 4194304ull
#define WL_OFF 6291456ull
#define KD_OFF 8388608ull

__device__ __forceinline__ unsigned short bf16_rne(float f) {
    unsigned int u = __float_as_uint(f);
    u += 0x7FFFu + ((u >> 16) & 1u);
    return (unsigned short)(u >> 16);
}
__device__ __forceinline__ float bf16_f32(unsigned short h) {
    return __uint_as_float(((unsigned int)h) << 16);
}

// ---------------- prep: swizzle kernels into frag-linear hi/lo bf16 ----------------
__global__ __launch_bounds__(256) void ife_prep(const float* __restrict__ kern,
                                                unsigned char* __restrict__ ws)
{
    const int ja = blockIdx.x;           // j*8 + a
    const int t = threadIdx.x;
    const int fragid = t >> 6;           // 0..3
    const int lane = t & 63;
    const int q = lane >> 4;
    const int c = lane & 15;
    const float* src = kern + (size_t)ja * (F_ * U_);
    const size_t off = (size_t)ja * 4096 + (size_t)fragid * 1024 + (size_t)lane * 16;

    if (blockIdx.y == 0) {
        // Z-GEMM B-frags from K
        const int utile = fragid & 1, kc = fragid >> 1;
        const int u = utile * 16 + c;
        const int f0 = kc * 32 + q * 8;
        unsigned int hw[4], lw[4];
        #pragma unroll
        for (int i = 0; i < 4; ++i) {
            const float v0 = src[(f0 + 2 * i) * U_ + u];
            const float v1 = src[(f0 + 2 * i + 1) * U_ + u];
            const unsigned short h0 = bf16_rne(v0), h1 = bf16_rne(v1);
            const unsigned short l0 = bf16_rne(v0 - bf16_f32(h0));
            const unsigned short l1 = bf16_rne(v1 - bf16_f32(h1));
            hw[i] = (unsigned int)h0 | ((unsigned int)h1 << 16);
            lw[i] = (unsigned int)l0 | ((unsigned int)l1 << 16);
        }
        *(uint4*)(ws + KH_OFF + off) = make_uint4(hw[0], hw[1], hw[2], hw[3]);
        *(uint4*)(ws + KL_OFF + off) = make_uint4(lw[0], lw[1], lw[2], lw[3]);
    } else {
        // S-GEMM B-frags from W = exp(2K)
        const int f = fragid * 16 + c;
        const int u0 = q * 8;
        const float4 va = *(const float4*)&src[f * U_ + u0];
        const float4 vb = *(const float4*)&src[f * U_ + u0 + 4];
        const float vv[8] = {va.x, va.y, va.z, va.w, vb.x, vb.y, vb.z, vb.w};
        unsigned int hw[4], lw[4];
        #pragma unroll
        for (int i = 0; i < 4; ++i) {
            const float w0 = __expf(2.f * vv[2 * i]);
            const float w1 = __expf(2.f * vv[2 * i + 1]);
            const unsigned short h0 = bf16_rne(w0), h1 = bf16_rne(w1);
            const unsigned short l0 = bf16_rne(w0 - bf16_f32(h0));
            const unsigned short l1 = bf16_rne(w1 - bf16_f32(h1));
            hw[i] = (unsigned int)h0 | ((unsigned int)h1 << 16);
            lw[i] = (unsigned int)l0 | ((unsigned int)l1 << 16);
        }
        *(uint4*)(ws + WH_OFF + off) = make_uint4(hw[0], hw[1], hw[2], hw[3]);
        *(uint4*)(ws + WL_OFF + off) = make_uint4(lw[0], lw[1], lw[2], lw[3]);
        if (t < U_) {
            const int j = ja >> 3;
            ((float*)(ws + KD_OFF))[(size_t)ja * U_ + t] = src[j * U_ + t];
        }
    }
}

// 16B global->LDS direct copy; lane-contiguous pattern (wave-uniform base + lane*16)
__device__ __forceinline__ void gload_lds16(const unsigned char* g, unsigned char* l)
{
    __builtin_amdgcn_global_load_lds(
        (const __attribute__((address_space(1))) void*)(unsigned long long)(uintptr_t)g,
        (__attribute__((address_space(3))) void*)(unsigned int)(uintptr_t)l,
        16, 0, 0);
}

// ---------------- main: per (a, 64-row batch tile); wave handles 16 rows ----------------
__global__ __launch_bounds__(256, 2) void ife_main(const float* __restrict__ x,
                                                   const unsigned char* __restrict__ ws,
                                                   float* __restrict__ out)
{
    const int a = blockIdx.y, bt = blockIdx.x;
    const int t = threadIdx.x;
    const int wv = t >> 6, lane = t & 63, q = lane >> 4, c = lane & 15;

    __shared__ unsigned char stage[2][16384];      // [Kh 4K][Kl 4K][Wh 4K][Wl 4K]
    __shared__ unsigned int Pbuf[4][16][36];       // per-wave P, packed (ph | pl<<16), stride 36 words
    __shared__ float Xf[64][65];                   // fp32 X tile for mask correction (padded)
    __shared__ float Kd[64][32];                   // Kdiag[j][u] for this a

    // --- build this wave's X A-frags (m=c, k=kc*32+q*8+jj), split hi/lo ---
    bf16x8 Xh[2], Xl[2];
    {
        const float* xr = x + (size_t)(bt * 64 + wv * 16 + c) * F_;
        #pragma unroll
        for (int kc = 0; kc < 2; ++kc) {
            const float4 va = *(const float4*)&xr[kc * 32 + q * 8];
            const float4 vb = *(const float4*)&xr[kc * 32 + q * 8 + 4];
            const float vv[8] = {va.x, va.y, va.z, va.w, vb.x, vb.y, vb.z, vb.w};
            union { unsigned int u[4]; bf16x8 v; } H, L;
            #pragma unroll
            for (int i = 0; i < 4; ++i) {
                const unsigned short h0 = bf16_rne(vv[2 * i]), h1 = bf16_rne(vv[2 * i + 1]);
                const unsigned short l0 = bf16_rne(vv[2 * i] - bf16_f32(h0));
                const unsigned short l1 = bf16_rne(vv[2 * i + 1] - bf16_f32(h1));
                H.u[i] = (unsigned int)h0 | ((unsigned int)h1 << 16);
                L.u[i] = (unsigned int)l0 | ((unsigned int)l1 << 16);
            }
            Xh[kc] = H.v; Xl[kc] = L.v;
        }
    }
    // --- stage fp32 X tile (for correction reads, broadcast-friendly) ---
    {
        const int row = t >> 2, cb = (t & 3) * 16;
        const float* xsrc = x + (size_t)(bt * 64 + row) * F_ + cb;
        #pragma unroll
        for (int i = 0; i < 16; i += 4) {
            const float4 v = *(const float4*)&xsrc[i];
            Xf[row][cb + i] = v.x; Xf[row][cb + i + 1] = v.y;
            Xf[row][cb + i + 2] = v.z; Xf[row][cb + i + 3] = v.w;
        }
    }
    // --- stage Kdiag for this a ---
    {
        const int j0 = t >> 2, u0 = (t & 3) * 8;
        const float* ksrc = (const float*)(ws + KD_OFF) + ((size_t)j0 * A_ + a) * U_ + u0;
        *(float4*)&Kd[j0][u0] = *(const float4*)ksrc;
        *(float4*)&Kd[j0][u0 + 4] = *(const float4*)(ksrc + 4);
    }
    // --- prefetch j=0 staging ---
    {
        const size_t off = (size_t)(0 * A_ + a) * 4096 + (size_t)t * 16;
        #pragma unroll
        for (int s = 0; s < 4; ++s)
            gload_lds16(ws + (size_t)s * 2097152ull + off, &stage[0][s * 4096 + t * 16]);
    }
    __syncthreads();

    f32x4 S[4];
    #pragma unroll
    for (int i = 0; i < 4; ++i) S[i] = (f32x4){0.f, 0.f, 0.f, 0.f};

    for (int j = 0; j < F_; ++j) {
        // 1. prefetch next (j=63 wraps to 0; harmless)
        {
            const int jn = (j + 1) & 63;
            const size_t off = (size_t)(jn * A_ + a) * 4096 + (size_t)t * 16;
            unsigned char* dbuf = stage[(j + 1) & 1];
            #pragma unroll
            for (int s = 0; s < 4; ++s)
                gload_lds16(ws + (size_t)s * 2097152ull + off, &dbuf[s * 4096 + t * 16]);
        }
        const unsigned char* buf = stage[j & 1];

        // 2. K B-frags (conflict-free lane-linear b128)
        bf16x8 KhF[2][2], KlF[2][2];   // [utile][kc]
        #pragma unroll
        for (int ut = 0; ut < 2; ++ut)
            #pragma unroll
            for (int kc = 0; kc < 2; ++kc) {
                KhF[ut][kc] = *(const bf16x8*)(buf + (kc * 2 + ut) * 1024 + lane * 16);
                KlF[ut][kc] = *(const bf16x8*)(buf + 4096 + (kc * 2 + ut) * 1024 + lane * 16);
            }

        // 3. Z = X @ K  (split-bf16: hh + hl + lh)
        f32x4 ZA = (f32x4){0.f, 0.f, 0.f, 0.f}, ZB = ZA;
        #pragma unroll
        for (int kc = 0; kc < 2; ++kc) {
            ZA = __builtin_amdgcn_mfma_f32_16x16x32_bf16(Xh[kc], KhF[0][kc], ZA, 0, 0, 0);
            ZA = __builtin_amdgcn_mfma_f32_16x16x32_bf16(Xl[kc], KhF[0][kc], ZA, 0, 0, 0);
            ZA = __builtin_amdgcn_mfma_f32_16x16x32_bf16(Xh[kc], KlF[0][kc], ZA, 0, 0, 0);
            ZB = __builtin_amdgcn_mfma_f32_16x16x32_bf16(Xh[kc], KhF[1][kc], ZB, 0, 0, 0);
            ZB = __builtin_amdgcn_mfma_f32_16x16x32_bf16(Xl[kc], KhF[1][kc], ZB, 0, 0, 0);
            ZB = __builtin_amdgcn_mfma_f32_16x16x32_bf16(Xh[kc], KlF[1][kc], ZB, 0, 0, 0);
        }

        // 4. W B-frags now (all stage reads must precede the barrier)
        bf16x8 WhF[4], WlF[4];
        #pragma unroll
        for (int ft = 0; ft < 4; ++ft) {
            WhF[ft] = *(const bf16x8*)(buf + 8192 + ft * 1024 + lane * 16);
            WlF[ft] = *(const bf16x8*)(buf + 12288 + ft * 1024 + lane * 16);
        }

        // 5. rank-1 mask correction + softmax over u + P write (hi/lo packed)
        {
            const float kd0 = Kd[j][c], kd1 = Kd[j][16 + c];
            #pragma unroll
            for (int r = 0; r < 4; ++r) {
                const float xj = Xf[wv * 16 + q * 4 + r][j];
                float z0 = ZA[r] - xj * kd0;
                float z1 = ZB[r] - xj * kd1;
                float m = fmaxf(z0, z1);
                m = fmaxf(m, __shfl_xor(m, 1));
                m = fmaxf(m, __shfl_xor(m, 2));
                m = fmaxf(m, __shfl_xor(m, 4));
                m = fmaxf(m, __shfl_xor(m, 8));
                const float e0 = __expf(z0 - m), e1 = __expf(z1 - m);
                float s = e0 + e1;
                s += __shfl_xor(s, 1);
                s += __shfl_xor(s, 2);
                s += __shfl_xor(s, 4);
                s += __shfl_xor(s, 8);
                const float inv = 1.f / s;
                const float p0 = e0 * inv, p1 = e1 * inv;
                const unsigned short h0 = bf16_rne(p0);
                const unsigned short l0 = bf16_rne(p0 - bf16_f32(h0));
                const unsigned short h1 = bf16_rne(p1);
                const unsigned short l1 = bf16_rne(p1 - bf16_f32(h1));
                Pbuf[wv][q * 4 + r][c] = (unsigned int)h0 | ((unsigned int)l0 << 16);
                Pbuf[wv][q * 4 + r][16 + c] = (unsigned int)h1 | ((unsigned int)l1 << 16);
            }
        }

        // 6. single barrier per j: drains staging prefetch (vmcnt) for next iter,
        //    protects stage buffer reuse, makes Pbuf visible.
        __syncthreads();

        // 7. P A-frags (m=c, k=u=q*8+jj): unpack hi/lo via byte-perm
        union { unsigned int u[4]; bf16x8 v; } PH, PL;
        {
            const uint4 pa = *(const uint4*)&Pbuf[wv][c][q * 8];
            const uint4 pb = *(const uint4*)&Pbuf[wv][c][q * 8 + 4];
            PH.u[0] = __builtin_amdgcn_perm(pa.y, pa.x, 0x05040100u);
            PH.u[1] = __builtin_amdgcn_perm(pa.w, pa.z, 0x05040100u);
            PH.u[2] = __builtin_amdgcn_perm(pb.y, pb.x, 0x05040100u);
            PH.u[3] = __builtin_amdgcn_perm(pb.w, pb.z, 0x05040100u);
            PL.u[0] = __builtin_amdgcn_perm(pa.y, pa.x, 0x07060302u);
            PL.u[1] = __builtin_amdgcn_perm(pa.w, pa.z, 0x07060302u);
            PL.u[2] = __builtin_amdgcn_perm(pb.y, pb.x, 0x07060302u);
            PL.u[3] = __builtin_amdgcn_perm(pb.w, pb.z, 0x07060302u);
        }

        // 8. S += P @ W^T (split-bf16: hh + hl + lh)
        #pragma unroll
        for (int ft = 0; ft < 4; ++ft) {
            S[ft] = __builtin_amdgcn_mfma_f32_16x16x32_bf16(PH.v, WhF[ft], S[ft], 0, 0, 0);
            S[ft] = __builtin_amdgcn_mfma_f32_16x16x32_bf16(PH.v, WlF[ft], S[ft], 0, 0, 0);
            S[ft] = __builtin_amdgcn_mfma_f32_16x16x32_bf16(PL.v, WhF[ft], S[ft], 0, 0, 0);
        }
    }

    // ---- epilogue: mean over j, softmax over f, store ----
    const float sc = 1.f / 64.f;
    #pragma unroll
    for (int r = 0; r < 4; ++r) {
        const float v0 = S[0][r] * sc, v1 = S[1][r] * sc, v2 = S[2][r] * sc, v3 = S[3][r] * sc;
        float m = fmaxf(fmaxf(v0, v1), fmaxf(v2, v3));
        m = fmaxf(m, __shfl_xor(m, 1));
        m = fmaxf(m, __shfl_xor(m, 2));
        m = fmaxf(m, __shfl_xor(m, 4));
        m = fmaxf(m, __shfl_xor(m, 8));
        const float e0 = __expf(v0 - m), e1 = __expf(v1 - m);
        const float e2 = __expf(v2 - m), e3 = __expf(v3 - m);
        float s = e0 + e1 + e2 + e3;
        s += __shfl_xor(s, 1);
        s += __shfl_xor(s, 2);
        s += __shfl_xor(s, 4);
        s += __shfl_xor(s, 8);
        const float inv = 1.f / s;
        const int b = bt * 64 + wv * 16 + q * 4 + r;
        float* o = out + ((size_t)a * B_ + b) * F_ + c;
        o[0]  = e0 * inv;
        o[16] = e1 * inv;
        o[32] = e2 * inv;
        o[48] = e3 * inv;
    }
}

extern "C" void kernel_launch(void* const* d_in, const int* in_sizes, int n_in,
                              void* d_out, int out_size, void* d_ws, size_t ws_size,
                              hipStream_t stream) {
    (void)in_sizes; (void)n_in; (void)out_size; (void)ws_size;
    const float* x    = (const float*)d_in[0];   // [B, F]
    const float* kern = (const float*)d_in[1];   // [F, A, F, U]
    float* out        = (float*)d_out;           // [A, B, F]
    unsigned char* ws = (unsigned char*)d_ws;    // needs ~8.1 MB

    hipLaunchKernelGGL(ife_prep, dim3(F_ * A_, 2), dim3(256), 0, stream, kern, ws);
    hipLaunchKernelGGL(ife_main, dim3(B_ / 64, A_), dim3(256), 0, stream, x, ws, out);
}

// Round 3
// 98.161 us; speedup vs baseline: 4.3421x; 1.8865x over previous
//
#include <hip/hip_runtime.h>
#include <hip/hip_bf16.h>
#include <math.h>

#define B_ 4096
#define F_ 64
#define A_ 8
#define U_ 32

typedef float f32x4 __attribute__((ext_vector_type(4)));
typedef short bf16x8 __attribute__((ext_vector_type(8)));

// ws layout:
//   [0, 4 MB): frag blob, per (a,j) 8192 B, index (a*64+j):
//     [0,4096):  K B-frags, fragid = kc*2+ut, 64 lanes x 16 B:
//                bf16 K[f = kc*32 + q*8 + jj][u = ut*16 + c]
//     [4096,8192): W B-frags, fragid = ft:
//                bf16 exp(2*K[f = ft*16 + c][u = q*8 + jj])
//   [4 MB, 4 MB + 64 KB): Kd fp32 (bf16-rounded values): [a*64+j][32] = K[j,a][j][u]
#define KD_OFF (4ull << 20)

static __device__ __forceinline__ unsigned int pk_bf16(float lo, float hi) {
    union { __hip_bfloat162 h2; unsigned int u; } cv;
    cv.h2 = __float22bfloat162_rn(make_float2(lo, hi));
    return cv.u;
}
// round fp32 -> bf16 -> fp32 (match what the MFMA actually sees)
static __device__ __forceinline__ float rb(float f) {
    unsigned int u = __float_as_uint(f);
    u += 0x7FFFu + ((u >> 16) & 1u);
    return __uint_as_float(u & 0xFFFF0000u);
}

// ---------------- prep: one block per (a,j); stage 8 KB, emit frags + Kd ----------------
__global__ __launch_bounds__(256) void ife_prep(const float* __restrict__ kern,
                                                unsigned char* __restrict__ ws)
{
    const int bid = blockIdx.x;           // a*64 + j
    const int a = bid >> 6, j = bid & 63;
    const int t = threadIdx.x;
    __shared__ float st[64][36];          // [f][u], pitch 36 (16B-aligned float4 slots)

    const float* src = kern + ((size_t)j * A_ + a) * (F_ * U_);
    {
        const int f = t >> 2, u0 = (t & 3) * 8;
        *(float4*)&st[f][u0]     = *(const float4*)&src[f * U_ + u0];
        *(float4*)&st[f][u0 + 4] = *(const float4*)&src[f * U_ + u0 + 4];
    }
    __syncthreads();

    unsigned char* dst = ws + (size_t)bid * 8192;
    const int fragid = t >> 6, lane = t & 63, q = lane >> 4, c = lane & 15;

    // K B-frag (fragid = kc*2 + ut)
    {
        const int kc = fragid >> 1, ut = fragid & 1;
        const int f0 = kc * 32 + q * 8, u = ut * 16 + c;
        unsigned int w[4];
        #pragma unroll
        for (int i = 0; i < 4; ++i)
            w[i] = pk_bf16(st[f0 + 2 * i][u], st[f0 + 2 * i + 1][u]);
        *(uint4*)(dst + fragid * 1024 + lane * 16) = make_uint4(w[0], w[1], w[2], w[3]);
    }
    // W B-frag (fragid = ft)
    {
        const int f = fragid * 16 + c, u0 = q * 8;
        const float4 wa = *(const float4*)&st[f][u0];
        const float4 wb = *(const float4*)&st[f][u0 + 4];
        unsigned int w[4];
        w[0] = pk_bf16(__expf(2.f * wa.x), __expf(2.f * wa.y));
        w[1] = pk_bf16(__expf(2.f * wa.z), __expf(2.f * wa.w));
        w[2] = pk_bf16(__expf(2.f * wb.x), __expf(2.f * wb.y));
        w[3] = pk_bf16(__expf(2.f * wb.z), __expf(2.f * wb.w));
        *(uint4*)(dst + 4096 + fragid * 1024 + lane * 16) = make_uint4(w[0], w[1], w[2], w[3]);
    }
    // Kd (bf16-rounded so the rank-1 correction exactly cancels the MFMA j-term)
    if (t < U_)
        ((float*)(ws + KD_OFF))[(size_t)bid * U_ + t] = rb(st[j][t]);
}

// ---------------- main: (a, 64-row tile); wave = 16 rows; NO barrier in j-loop ----------------
__global__ __launch_bounds__(256, 2) void ife_main(const float* __restrict__ x,
                                                   const unsigned char* __restrict__ ws,
                                                   float* __restrict__ out)
{
    const int a = blockIdx.y, bt = blockIdx.x, t = threadIdx.x;
    const int wv = t >> 6, lane = t & 63, q = lane >> 4, c = lane & 15;

    __shared__ float Xf[64][66];                       // bf16-rounded fp32 X tile
    __shared__ float Kd[64][32];                       // bf16-rounded K[j][j][u] for this a
    __shared__ __align__(16) unsigned int Pbuf[4][16][20];  // wave-private E, pitch 20 dwords

    // X A-frags (m = c, k = kc*32 + q*8 + jj), pure bf16
    bf16x8 Xh[2];
    {
        const float* xr = x + (size_t)(bt * 64 + wv * 16 + c) * F_;
        #pragma unroll
        for (int kc = 0; kc < 2; ++kc) {
            const float4 va = *(const float4*)&xr[kc * 32 + q * 8];
            const float4 vb = *(const float4*)&xr[kc * 32 + q * 8 + 4];
            union { unsigned int u[4]; bf16x8 v; } H;
            H.u[0] = pk_bf16(va.x, va.y);
            H.u[1] = pk_bf16(va.z, va.w);
            H.u[2] = pk_bf16(vb.x, vb.y);
            H.u[3] = pk_bf16(vb.z, vb.w);
            Xh[kc] = H.v;
        }
    }
    // Xf (bf16-rounded values, fp32 storage, broadcast-friendly)
    {
        const int row = t >> 2, cb = (t & 3) * 16;
        const float* xsrc = x + (size_t)(bt * 64 + row) * F_ + cb;
        #pragma unroll
        for (int i = 0; i < 16; i += 4) {
            const float4 v = *(const float4*)&xsrc[i];
            Xf[row][cb + i]     = rb(v.x);
            Xf[row][cb + i + 1] = rb(v.y);
            Xf[row][cb + i + 2] = rb(v.z);
            Xf[row][cb + i + 3] = rb(v.w);
        }
    }
    // Kd stage (contiguous 8 KB)
    {
        const float* kd = (const float*)(ws + KD_OFF) + (size_t)a * 64 * U_;
        const int jj = t >> 2, u0 = (t & 3) * 8;
        *(float4*)&Kd[jj][u0]     = *(const float4*)&kd[jj * U_ + u0];
        *(float4*)&Kd[jj][u0 + 4] = *(const float4*)&kd[jj * U_ + u0 + 4];
    }
    __syncthreads();   // the only block-wide barrier

    const unsigned int psel = (q < 2) ? 0x05040100u : 0x07060302u;
    const unsigned char* fbase = ws + (size_t)a * 64 * 8192 + (size_t)lane * 16;

    union { unsigned int u[4]; bf16x8 v; } oc;
    oc.u[0] = 0x3F803F80u; oc.u[1] = 0x3F803F80u; oc.u[2] = 0x3F803F80u; oc.u[3] = 0x3F803F80u;
    const bf16x8 ONES = oc.v;
    const f32x4 vzero = (f32x4){0.f, 0.f, 0.f, 0.f};

    f32x4 S0 = vzero, S1 = vzero, S2 = vzero, S3 = vzero;

    bf16x8 KA[4], WA[4], KB[4], WB[4];

    auto LOADF = [&](bf16x8* K, bf16x8* W, int jj) {
        const unsigned char* p = fbase + (size_t)jj * 8192;
        #pragma unroll
        for (int i = 0; i < 4; ++i) {
            K[i] = *(const bf16x8*)(p + i * 1024);
            W[i] = *(const bf16x8*)(p + 4096 + i * 1024);
        }
    };

    auto BODY = [&](const bf16x8* K, const bf16x8* W, int j) {
        // Z = X @ K (pure bf16)
        f32x4 ZA = vzero, ZB = vzero;
        ZA = __builtin_amdgcn_mfma_f32_16x16x32_bf16(Xh[0], K[0], ZA, 0, 0, 0);
        ZA = __builtin_amdgcn_mfma_f32_16x16x32_bf16(Xh[1], K[2], ZA, 0, 0, 0);
        ZB = __builtin_amdgcn_mfma_f32_16x16x32_bf16(Xh[0], K[1], ZB, 0, 0, 0);
        ZB = __builtin_amdgcn_mfma_f32_16x16x32_bf16(Xh[1], K[3], ZB, 0, 0, 0);

        // rank-1 mask correction + exp (no max subtraction), write unnormalized E
        const float kd0 = Kd[j][c], kd1 = Kd[j][16 + c];
        #pragma unroll
        for (int r = 0; r < 4; ++r) {
            const float xj = Xf[wv * 16 + q * 4 + r][j];
            const float e0 = __expf(ZA[r] - xj * kd0);
            const float e1 = __expf(ZB[r] - xj * kd1);
            Pbuf[wv][q * 4 + r][c] = pk_bf16(e0, e1);
        }
        // wave-internal LDS round-trip: drain writes, then read A-frag
        asm volatile("s_waitcnt lgkmcnt(0)" ::: "memory");
        union { unsigned int u[4]; bf16x8 v; } E;
        {
            const uint4 pa = *(const uint4*)&Pbuf[wv][c][(q & 1) * 8];
            const uint4 pb = *(const uint4*)&Pbuf[wv][c][(q & 1) * 8 + 4];
            E.u[0] = __builtin_amdgcn_perm(pa.y, pa.x, psel);
            E.u[1] = __builtin_amdgcn_perm(pa.w, pa.z, psel);
            E.u[2] = __builtin_amdgcn_perm(pb.y, pb.x, psel);
            E.u[3] = __builtin_amdgcn_perm(pb.w, pb.z, psel);
        }

        // row sums via MFMA against ones; normalize after the GEMM
        const f32x4 sv = __builtin_amdgcn_mfma_f32_16x16x32_bf16(E.v, ONES, vzero, 0, 0, 0);
        f32x4 D0 = __builtin_amdgcn_mfma_f32_16x16x32_bf16(E.v, W[0], vzero, 0, 0, 0);
        f32x4 D1 = __builtin_amdgcn_mfma_f32_16x16x32_bf16(E.v, W[1], vzero, 0, 0, 0);
        f32x4 D2 = __builtin_amdgcn_mfma_f32_16x16x32_bf16(E.v, W[2], vzero, 0, 0, 0);
        f32x4 D3 = __builtin_amdgcn_mfma_f32_16x16x32_bf16(E.v, W[3], vzero, 0, 0, 0);
        #pragma unroll
        for (int r = 0; r < 4; ++r) {
            const float inv = __builtin_amdgcn_rcpf(sv[r]);
            S0[r] += D0[r] * inv;
            S1[r] += D1[r] * inv;
            S2[r] += D2[r] * inv;
            S3[r] += D3[r] * inv;
        }
    };

    LOADF(KA, WA, 0);
    for (int j = 0; j < 64; j += 2) {
        LOADF(KB, WB, j + 1);
        BODY(KA, WA, j);
        LOADF(KA, WA, (j + 2 < 64) ? (j + 2) : 63);
        BODY(KB, WB, j + 1);
    }

    // epilogue: mean over j, softmax over f (flat scores -> no max needed)
    const float sc = 1.f / 64.f;
    #pragma unroll
    for (int r = 0; r < 4; ++r) {
        const float e0 = __expf(S0[r] * sc);
        const float e1 = __expf(S1[r] * sc);
        const float e2 = __expf(S2[r] * sc);
        const float e3 = __expf(S3[r] * sc);
        float s = e0 + e1 + e2 + e3;
        s += __shfl_xor(s, 1);
        s += __shfl_xor(s, 2);
        s += __shfl_xor(s, 4);
        s += __shfl_xor(s, 8);
        const float inv = 1.f / s;
        const int b = bt * 64 + wv * 16 + q * 4 + r;
        float* o = out + ((size_t)a * B_ + b) * F_ + c;
        o[0]  = e0 * inv;
        o[16] = e1 * inv;
        o[32] = e2 * inv;
        o[48] = e3 * inv;
    }
}

extern "C" void kernel_launch(void* const* d_in, const int* in_sizes, int n_in,
                              void* d_out, int out_size, void* d_ws, size_t ws_size,
                              hipStream_t stream) {
    (void)in_sizes; (void)n_in; (void)out_size; (void)ws_size;
    const float* x    = (const float*)d_in[0];   // [B, F]
    const float* kern = (const float*)d_in[1];   // [F, A, F, U]
    float* out        = (float*)d_out;           // [A, B, F]
    unsigned char* ws = (unsigned char*)d_ws;    // ~4.1 MB used

    hipLaunchKernelGGL(ife_prep, dim3(F_ * A_), dim3(256), 0, stream, kern, ws);
    hipLaunchKernelGGL(ife_main, dim3(B_ / 64, A_), dim3(256), 0, stream, x, ws, out);
}